// Round 1
// baseline (455.585 us; speedup 1.0000x reference)
//
#include <hip/hip_runtime.h>
#include <hip/hip_bf16.h>

// Problem dims (fixed by the reference):
//   x: (256*14*14, 384) fp32  -> M = 50176, K = 384
//   W: (1536, 384) fp32       -> N = 1536 (row-major N x K, i.e. B^T layout)
//   out: (M, N) fp32
#define M_ROWS 50176
#define K_DIM  384
#define N_DIM  1536

typedef __bf16 bf16;
typedef bf16  bf16x8 __attribute__((ext_vector_type(8)));
typedef float f32x4  __attribute__((ext_vector_type(4)));

typedef __attribute__((address_space(1))) const void* addr1_cptr;
typedef __attribute__((address_space(3))) void*       addr3_ptr;

// Async global->LDS, 16B per lane. LDS dest = wave-uniform base + lane*16.
__device__ __forceinline__ void async_copy16(const void* g, void* l) {
    __builtin_amdgcn_global_load_lds((addr1_cptr)g, (addr3_ptr)l, 16, 0, 0);
}

// ---------------------------------------------------------------------------
// Kernel 1: LayerNorm over last dim (384), fp32 in -> bf16 out.
// One wave per row; lane holds 3 float2 (6 elems).
// ---------------------------------------------------------------------------
__global__ __launch_bounds__(256) void ln_kernel(
    const float* __restrict__ x, const float* __restrict__ gamma,
    const float* __restrict__ beta, bf16* __restrict__ xn) {
    const int t = threadIdx.x;
    const int wave = t >> 6, lane = t & 63;
    const long row = (long)blockIdx.x * 4 + wave;

    const float2* xr = (const float2*)(x + row * K_DIM);
    float2 v[3];
    v[0] = xr[lane];
    v[1] = xr[lane + 64];
    v[2] = xr[lane + 128];

    float s = v[0].x + v[0].y + v[1].x + v[1].y + v[2].x + v[2].y;
    float q = v[0].x * v[0].x + v[0].y * v[0].y + v[1].x * v[1].x +
              v[1].y * v[1].y + v[2].x * v[2].x + v[2].y * v[2].y;
#pragma unroll
    for (int off = 32; off > 0; off >>= 1) {
        s += __shfl_xor(s, off);
        q += __shfl_xor(q, off);
    }
    const float mean = s * (1.0f / K_DIM);
    const float var  = q * (1.0f / K_DIM) - mean * mean;
    const float rstd = rsqrtf(var + 1e-6f);

    const float2* g2 = (const float2*)gamma;
    const float2* b2 = (const float2*)beta;
    bf16* orow = xn + row * K_DIM;
#pragma unroll
    for (int i = 0; i < 3; ++i) {
        float2 g  = g2[lane + i * 64];
        float2 bb = b2[lane + i * 64];
        float y0 = (v[i].x - mean) * rstd * g.x + bb.x;
        float y1 = (v[i].y - mean) * rstd * g.y + bb.y;
        __hip_bfloat162 h;
        h.x = __float2bfloat16(y0);
        h.y = __float2bfloat16(y1);
        *(__hip_bfloat162*)(orow + (lane + i * 64) * 2) = h;
    }
}

// ---------------------------------------------------------------------------
// Kernel 2: W fp32 -> bf16 (1536*384 elems, 2 per thread)
// ---------------------------------------------------------------------------
__global__ __launch_bounds__(256) void wcvt_kernel(
    const float* __restrict__ W, bf16* __restrict__ Wb) {
    const int i = blockIdx.x * 256 + threadIdx.x;  // over float2, count 294912
    float2 v = ((const float2*)W)[i];
    __hip_bfloat162 h;
    h.x = __float2bfloat16(v.x);
    h.y = __float2bfloat16(v.y);
    ((__hip_bfloat162*)Wb)[i] = h;
}

// ---------------------------------------------------------------------------
// Kernel 3: GEMM C = A(M x K, bf16) @ W^T (W is N x K, bf16) + bias, GELU.
// 128x128 block tile, BK=32, 4 waves each computing a 64x64 quadrant as
// 4x4 grid of 16x16x32 MFMA tiles. global_load_lds width=16 staging with
// XOR chunk swizzle (slot_chunk = chunk ^ ((row>>1)&3)) to spread LDS banks.
// ---------------------------------------------------------------------------
__global__ __launch_bounds__(256) void gemm_kernel(
    const bf16* __restrict__ A,    // [M][K]
    const bf16* __restrict__ B,    // [N][K]  (= W in bf16)
    const float* __restrict__ bias,
    float* __restrict__ out) {
    __shared__ __align__(16) bf16 Alds[128 * 32];
    __shared__ __align__(16) bf16 Blds[128 * 32];

    const int t = threadIdx.x;
    const int wave = t >> 6, lane = t & 63;
    const int wr = wave >> 1, wc = wave & 1;     // 2x2 wave grid
    const int lr = lane & 15, quad = lane >> 4;  // MFMA lane decomposition
    const long m0 = (long)blockIdx.y * 128;
    const int  n0 = blockIdx.x * 128;

    f32x4 acc[4][4];
#pragma unroll
    for (int i = 0; i < 4; ++i)
#pragma unroll
        for (int j = 0; j < 4; ++j)
            acc[i][j] = (f32x4){0.f, 0.f, 0.f, 0.f};

    // Staging source/dest. Slot e (0..511): row = e>>2, slot_chunk = e&3,
    // holds global chunk gc = (e&3) ^ ((row>>1)&3). Each chunk = 8 bf16 = 16B.
    const bf16* gA[2];
    const bf16* gB[2];
    void* lA[2];
    void* lB[2];
#pragma unroll
    for (int qq = 0; qq < 2; ++qq) {
        const int e   = qq * 256 + wave * 64 + lane;
        const int row = e >> 2;
        const int gc  = (e & 3) ^ ((row >> 1) & 3);
        gA[qq] = A + (m0 + row) * K_DIM + gc * 8;
        gB[qq] = B + (long)(n0 + row) * K_DIM + gc * 8;
        lA[qq] = (void*)(Alds + (qq * 256 + wave * 64) * 8);  // wave-uniform
        lB[qq] = (void*)(Blds + (qq * 256 + wave * 64) * 8);
    }

    // LDS read base: row r = (quadrant row) + lr, k-chunk = quad, swizzled.
    const int sw = quad ^ ((lr >> 1) & 3);
    const bf16* Ard = Alds + (wr * 64 + lr) * 32 + sw * 8;
    const bf16* Brd = Blds + (wc * 64 + lr) * 32 + sw * 8;

    for (int kb = 0; kb < K_DIM / 32; ++kb) {
        async_copy16(gA[0], lA[0]);
        async_copy16(gA[1], lA[1]);
        async_copy16(gB[0], lB[0]);
        async_copy16(gB[1], lB[1]);
        gA[0] += 32; gA[1] += 32; gB[0] += 32; gB[1] += 32;
        __syncthreads();  // drains vmcnt(0): staging visible

        bf16x8 a[4], b[4];
#pragma unroll
        for (int i = 0; i < 4; ++i) a[i] = *(const bf16x8*)(Ard + i * 16 * 32);
#pragma unroll
        for (int j = 0; j < 4; ++j) b[j] = *(const bf16x8*)(Brd + j * 16 * 32);
#pragma unroll
        for (int i = 0; i < 4; ++i)
#pragma unroll
            for (int j = 0; j < 4; ++j)
                acc[i][j] = __builtin_amdgcn_mfma_f32_16x16x32_bf16(
                    a[i], b[j], acc[i][j], 0, 0, 0);
        __syncthreads();  // LDS reads done before next stage overwrites
    }

    // Epilogue: C/D layout col = lane&15, row = quad*4 + reg [m89/m91].
    float bb[4];
#pragma unroll
    for (int j = 0; j < 4; ++j) bb[j] = bias[n0 + wc * 64 + j * 16 + lr];

#pragma unroll
    for (int i = 0; i < 4; ++i) {
        const long grow0 = m0 + wr * 64 + i * 16 + quad * 4;
#pragma unroll
        for (int j = 0; j < 4; ++j) {
            const int gcol = n0 + wc * 64 + j * 16 + lr;
#pragma unroll
            for (int r = 0; r < 4; ++r) {
                float y = acc[i][j][r] + bb[j];
                // exact GELU: 0.5*y*(1+erf(y/sqrt(2)))
                float g = 0.5f * y * (1.0f + erff(y * 0.70710678118654752f));
                out[(grow0 + r) * (long)N_DIM + gcol] = g;
            }
        }
    }
}

extern "C" void kernel_launch(void* const* d_in, const int* in_sizes, int n_in,
                              void* d_out, int out_size, void* d_ws, size_t ws_size,
                              hipStream_t stream) {
    (void)in_sizes; (void)n_in; (void)out_size; (void)ws_size;
    const float* x     = (const float*)d_in[0];
    const float* gamma = (const float*)d_in[1];
    const float* beta  = (const float*)d_in[2];
    const float* W     = (const float*)d_in[3];
    const float* b     = (const float*)d_in[4];
    float* out = (float*)d_out;

    // Workspace layout: xn bf16 [M][K] then Wb bf16 [N][K] (~39.7 MB total).
    bf16* xn = (bf16*)d_ws;
    bf16* Wb = (bf16*)((char*)d_ws + (size_t)M_ROWS * K_DIM * sizeof(bf16));

    ln_kernel<<<M_ROWS / 4, 256, 0, stream>>>(x, gamma, beta, xn);
    wcvt_kernel<<<(N_DIM * K_DIM / 2) / 256, 256, 0, stream>>>(W, Wb);

    dim3 grid(N_DIM / 128, M_ROWS / 128);
    gemm_kernel<<<grid, 256, 0, stream>>>(xn, Wb, b, out);
}